// Round 8
// baseline (470.475 us; speedup 1.0000x reference)
//
#include <hip/hip_runtime.h>

typedef _Float16 f16;
typedef _Float16 f16x2 __attribute__((ext_vector_type(2)));
typedef _Float16 f16x8 __attribute__((ext_vector_type(8)));
typedef float    f32x4 __attribute__((ext_vector_type(4)));
typedef float    f32x16 __attribute__((ext_vector_type(16)));

#define DIM 128

union U8 { f16x8 v; unsigned int u[4]; };

// silu(x) = x / (1 + e^-x); v_exp_f32 is 2^x so scale by log2(e). v_rcp_f32 ~1ulp.
__device__ __forceinline__ float silu_f(float x) {
    float e = __builtin_amdgcn_exp2f(x * -1.44269504088896341f);
    return x * __builtin_amdgcn_rcpf(1.0f + e);
}

// r8: TRANSPOSED-OPERAND structure -- weights are MFMA arg1, activations arg2.
// Layer-1 output then has feature dim n1 in REGISTERS and row dim in LANES
// (C: m->regs r=(q)+(8rr)+(4h), n->l31), which is exactly the arg2 (B) orientation
// layer 2 needs. The half-wave residue gap (lane holds n1=4h..4h+3 mod 8, needs
// all 8) is fixed by ONE __shfl_xor(...,32) of 16 dwords/thread: lane L^32 holds
// the same row l31 with the other residues. This DELETES the entire x1 LDS
// round-trip + slab repack (~96 DS ops/thread/tile -> 16 swizzles), cutting the
// dominant serial-sum term (LDS ~21.5us). LDS = weights only (64 KB) -> 2
// blocks/CU = 16 waves/CU (4/SIMD), doubling phase diversity. Trig is computed
// per-frag inside the MFMA loop (trans pipe overlaps MFMA; af liveness 4 regs).
// Biases: n-dim is now in regs -> wave-uniform scalar loads + per-lane h-cndmask.
__global__ __launch_bounds__(512, 4)
void ts_mlp_kernel(const float* __restrict__ t,
                   const float* __restrict__ W1, const float* __restrict__ b1,
                   const float* __restrict__ W2, const float* __restrict__ b2,
                   float* __restrict__ out, int B) {
    // Weight frags (arg1 / A-position), layout [n -> l31][k -> kt*16 + h*8 + j]:
    // w?f[kt][nt][lane] holds W[n = nt*32 + (L&31)][k = kt*16 + (L>>5)*8 + j]
    __shared__ f16x8 w1f[8][4][64];     // 32 KB
    __shared__ f16x8 w2f[8][4][64];     // 32 KB

    const int tid  = threadIdx.x;
    const int wv   = tid >> 6;
    const int lane = tid & 63;
    const int h    = lane >> 5;    // half-wave index
    const int l31  = lane & 31;

    // ---- prologue: wave wv stages k-tile kt=wv of both matrices -> LDS frags
    {
        const int kt = wv;
        const int k0 = kt * 16 + h * 8;
#pragma unroll
        for (int mtx = 0; mtx < 2; ++mtx) {
            const float* W = mtx ? W2 : W1;
#pragma unroll
            for (int nt = 0; nt < 4; ++nt) {
                const int n = nt * 32 + l31;
                const float4* src = (const float4*)(W + n * DIM + k0);
                float4 lo = src[0], hi = src[1];
                f16x8 fr;
                fr[0] = (f16)lo.x; fr[1] = (f16)lo.y; fr[2] = (f16)lo.z; fr[3] = (f16)lo.w;
                fr[4] = (f16)hi.x; fr[5] = (f16)hi.y; fr[6] = (f16)hi.z; fr[7] = (f16)hi.w;
                if (mtx) w2f[kt][nt][lane] = fr; else w1f[kt][nt][lane] = fr;
            }
        }
    }
    __syncthreads();   // the ONLY barrier in the kernel

    const int ntiles = B >> 8;            // 256 rows per block-tile
    const int stride = gridDim.x;
    const float h8f = (float)(h * 8);

    int tile = blockIdx.x;
    float tv_next = (tile < ntiles) ? t[tile * 256 + wv * 32 + l31] : 0.0f;

#pragma unroll 1
    for (; tile < ntiles; tile += stride) {
        const float tv = tv_next;
        const int nxt = tile + stride;
        if (nxt < ntiles) tv_next = t[nxt * 256 + wv * 32 + l31];
        const int row0 = tile * 256 + wv * 32;

        // ---- layer 1: per kt, compute emb frag (row = l31, k = kt*16+h*8+j) and
        // feed 4 MFMAs. v_sin/v_cos take REVOLUTIONS: phase_d*t/2pi = d*t/256.
        const float t256 = tv * 0.00390625f;
        const float o256 = (1.0f - tv) * 0.00390625f;
        f32x16 acc[4];
#pragma unroll
        for (int nt = 0; nt < 4; ++nt)
#pragma unroll
            for (int r = 0; r < 16; ++r) acc[nt][r] = 0.0f;
#pragma unroll
        for (int kt = 0; kt < 8; ++kt) {
            f16x8 ef;
#pragma unroll
            for (int j = 0; j < 8; ++j) {
                const float fd = (float)(kt * 16 + j) + h8f;
                const float c  = __builtin_amdgcn_cosf(fd * t256);
                const float s  = __builtin_amdgcn_sinf(fd * o256);
                ef[j] = (f16)(tv * (c + s));
            }
#pragma unroll
            for (int nt = 0; nt < 4; ++nt) {
                acc[nt] = __builtin_amdgcn_mfma_f32_32x32x16_f16(
                    w1f[kt][nt][lane], ef, acc[nt], 0, 0, 0);
            }
        }

        // ---- epilogue 1: C layout: lane L reg r (frag nt) = x1[n1][row=l31],
        // n1 = 32nt + (r&3) + 8(r>>2) + 4h. Bias+silu, pack pairs to f16x2,
        // then exchange half the dwords with lane^32 (which holds the same row,
        // other n1 residues). Slot a = dword covering k={2a,2a+1}:
        // own a = 16nt+8(rr>>1... a=16nt+4rr+2h+qp; keep rr=2i+h, send rr=2i+(1-h).
        unsigned int K0[8], K1[8], R0[8], R1[8];   // indexed by kt2 = 2nt+i
#pragma unroll
        for (int nt = 0; nt < 4; ++nt) {
            unsigned int D[4][2];
#pragma unroll
            for (int rr = 0; rr < 4; ++rr) {
#pragma unroll
                for (int qp = 0; qp < 2; ++qp) {
                    const int r  = 4 * rr + 2 * qp;
                    const int nb = 32 * nt + 8 * rr + 2 * qp;   // n1 for h=0
                    const float z0 = acc[nt][r]     + (h ? b1[nb + 4] : b1[nb]);
                    const float z1 = acc[nt][r + 1] + (h ? b1[nb + 5] : b1[nb + 1]);
                    f16x2 p; p.x = (f16)silu_f(z0); p.y = (f16)silu_f(z1);
                    D[rr][qp] = __builtin_bit_cast(unsigned int, p);
                }
            }
#pragma unroll
            for (int i = 0; i < 2; ++i) {
                const unsigned int s0 = h ? D[2 * i][0] : D[2 * i + 1][0];
                const unsigned int s1 = h ? D[2 * i][1] : D[2 * i + 1][1];
                const unsigned int r0 = (unsigned int)__shfl_xor((int)s0, 32, 64);
                const unsigned int r1 = (unsigned int)__shfl_xor((int)s1, 32, 64);
                K0[2 * nt + i] = h ? D[2 * i + 1][0] : D[2 * i][0];
                K1[2 * nt + i] = h ? D[2 * i + 1][1] : D[2 * i][1];
                R0[2 * nt + i] = r0;
                R1[2 * nt + i] = r1;
            }
        }

        // ---- layer 2: assemble arg2 frags in-register (x1[row=l31][k=16kt+8h+j]):
        // kept pair sits at s=2h..2h+1, received pair at s=2(1-h)..; 32 MFMAs.
        f32x16 acc2[4];
#pragma unroll
        for (int nt = 0; nt < 4; ++nt)
#pragma unroll
            for (int r = 0; r < 16; ++r) acc2[nt][r] = 0.0f;
#pragma unroll
        for (int kt = 0; kt < 8; ++kt) {
            U8 bf;
            bf.u[0] = h ? R0[kt] : K0[kt];
            bf.u[1] = h ? R1[kt] : K1[kt];
            bf.u[2] = h ? K0[kt] : R0[kt];
            bf.u[3] = h ? K1[kt] : R1[kt];
#pragma unroll
            for (int nt = 0; nt < 4; ++nt) {
                acc2[nt] = __builtin_amdgcn_mfma_f32_32x32x16_f16(
                    w2f[kt][nt][lane], bf.v, acc2[nt], 0, 0, 0);
            }
        }

        // ---- epilogue 2: bias + silu; lane L holds out[row=l31][n2-regs];
        // store 16 float4 chunks: row (row0+l31), cols 32nt+8rr+4h .. +3.
        const size_t rbase = (size_t)(row0 + l31) * DIM;
#pragma unroll
        for (int nt = 0; nt < 4; ++nt) {
#pragma unroll
            for (int rr = 0; rr < 4; ++rr) {
                f32x4 o;
#pragma unroll
                for (int q = 0; q < 4; ++q) {
                    const int r  = 4 * rr + q;
                    const int nb = 32 * nt + 8 * rr + q;        // n2 for h=0
                    o[q] = silu_f(acc2[nt][r] + (h ? b2[nb + 4] : b2[nb]));
                }
                *(f32x4*)&out[rbase + 32 * nt + 8 * rr + 4 * h] = o;
            }
        }
    }
}

extern "C" void kernel_launch(void* const* d_in, const int* in_sizes, int n_in,
                              void* d_out, int out_size, void* d_ws, size_t ws_size,
                              hipStream_t stream) {
    const float* t  = (const float*)d_in[0];
    const float* W1 = (const float*)d_in[1];
    const float* b1 = (const float*)d_in[2];
    const float* W2 = (const float*)d_in[3];
    const float* b2 = (const float*)d_in[4];
    float* out = (float*)d_out;
    const int B = in_sizes[0];
    const int ntiles = B >> 8;              // 256 rows per block-tile
    // 64 KB LDS -> 2 blocks/CU; 512 blocks x 2 tiles each
    int grid = ntiles < 512 ? ntiles : 512;
    ts_mlp_kernel<<<dim3(grid), dim3(512), 0, stream>>>(t, W1, b1, W2, b2, out, B);
}

// Round 11
// 445.271 us; speedup vs baseline: 1.0566x; 1.0566x over previous
//
#include <hip/hip_runtime.h>

typedef _Float16 f16;
typedef _Float16 f16x2 __attribute__((ext_vector_type(2)));
typedef _Float16 f16x8 __attribute__((ext_vector_type(8)));
typedef float    f32x4 __attribute__((ext_vector_type(4)));
typedef float    f32x16 __attribute__((ext_vector_type(16)));

#define DIM 128

union U8 { f16x8 v; unsigned int u[4]; };

// silu(x) = x / (1 + e^-x); v_exp_f32 is 2^x so scale by log2(e). v_rcp_f32 ~1ulp.
__device__ __forceinline__ float silu_f(float x) {
    float e = __builtin_amdgcn_exp2f(x * -1.44269504088896341f);
    return x * __builtin_amdgcn_rcpf(1.0f + e);
}

// r9/r10/r11: TRANSPOSED-OPERAND structure (r8, functionally verified) with the
// register-pressure bug fixed. Weights are MFMA arg1, activations arg2; layer-1
// output has n1 in regs / rows in lanes == layer-2's arg2 orientation, so ONE
// __shfl_xor(..,32) per dword-pair replaces the whole x1 LDS round-trip.
// r8's failure: 48 per-lane GLOBAL bias loads inside the tile loop -> scheduler
// hoists them -> ~48 extra live regs -> spill to scratch (VGPR 64, FETCH 439 MB,
// 361us). Fix: biases staged once in LDS (1 KB), read per-tile as broadcast
// ds_read_b128 (2 distinct addrs/wave, conflict-free); launch_bounds(512,3)
// gives the allocator a 170-reg cap (need ~110). LDS 65.5 KB -> 2 blocks/CU.
// (r9 and r10 benches were infra failures -- container died before running;
// identical experiment resubmitted, pattern matches r6->r7 transient flakiness.)
__global__ __launch_bounds__(512, 3)
void ts_mlp_kernel(const float* __restrict__ t,
                   const float* __restrict__ W1, const float* __restrict__ b1,
                   const float* __restrict__ W2, const float* __restrict__ b2,
                   float* __restrict__ out, int B) {
    // Weight frags (arg1 / A-position): w?f[kt][nt][lane] holds
    // W[n = nt*32 + (L&31)][k = kt*16 + (L>>5)*8 + j], j=0..7
    __shared__ f16x8 w1f[8][4][64];     // 32 KB
    __shared__ f16x8 w2f[8][4][64];     // 32 KB
    __shared__ float b1s[DIM];          // 512 B
    __shared__ float b2s[DIM];          // 512 B

    const int tid  = threadIdx.x;
    const int wv   = tid >> 6;
    const int lane = tid & 63;
    const int h    = lane >> 5;    // half-wave index
    const int l31  = lane & 31;

    // ---- prologue: wave wv stages k-tile kt=wv of both matrices -> LDS frags
    {
        const int kt = wv;
        const int k0 = kt * 16 + h * 8;
#pragma unroll
        for (int mtx = 0; mtx < 2; ++mtx) {
            const float* W = mtx ? W2 : W1;
#pragma unroll
            for (int nt = 0; nt < 4; ++nt) {
                const int n = nt * 32 + l31;
                const float4* src = (const float4*)(W + n * DIM + k0);
                float4 lo = src[0], hi = src[1];
                f16x8 fr;
                fr[0] = (f16)lo.x; fr[1] = (f16)lo.y; fr[2] = (f16)lo.z; fr[3] = (f16)lo.w;
                fr[4] = (f16)hi.x; fr[5] = (f16)hi.y; fr[6] = (f16)hi.z; fr[7] = (f16)hi.w;
                if (mtx) w2f[kt][nt][lane] = fr; else w1f[kt][nt][lane] = fr;
            }
        }
    }
    if (tid < DIM) {
        b1s[tid] = b1[tid];
        b2s[tid] = b2[tid];
    }
    __syncthreads();   // the ONLY barrier in the kernel

    const int ntiles = B >> 8;            // 256 rows per block-tile
    const int stride = gridDim.x;
    const float h8f = (float)(h * 8);

    int tile = blockIdx.x;
    float tv_next = (tile < ntiles) ? t[tile * 256 + wv * 32 + l31] : 0.0f;

#pragma unroll 1
    for (; tile < ntiles; tile += stride) {
        const float tv = tv_next;
        const int nxt = tile + stride;
        if (nxt < ntiles) tv_next = t[nxt * 256 + wv * 32 + l31];
        const int row0 = tile * 256 + wv * 32;

        // ---- layer 1: per kt, compute emb frag (row = l31, k = kt*16+h*8+j) and
        // feed 4 MFMAs. v_sin/v_cos take REVOLUTIONS: phase_d*t/2pi = d*t/256.
        const float t256 = tv * 0.00390625f;
        const float o256 = (1.0f - tv) * 0.00390625f;
        f32x16 acc[4];
#pragma unroll
        for (int nt = 0; nt < 4; ++nt)
#pragma unroll
            for (int r = 0; r < 16; ++r) acc[nt][r] = 0.0f;
#pragma unroll
        for (int kt = 0; kt < 8; ++kt) {
            f16x8 ef;
#pragma unroll
            for (int j = 0; j < 8; ++j) {
                const float fd = (float)(kt * 16 + j) + h8f;
                const float c  = __builtin_amdgcn_cosf(fd * t256);
                const float s  = __builtin_amdgcn_sinf(fd * o256);
                ef[j] = (f16)(tv * (c + s));
            }
#pragma unroll
            for (int nt = 0; nt < 4; ++nt) {
                acc[nt] = __builtin_amdgcn_mfma_f32_32x32x16_f16(
                    w1f[kt][nt][lane], ef, acc[nt], 0, 0, 0);
            }
        }

        // ---- epilogue 1: C layout: lane L reg r (frag nt) = x1[n1][row=l31],
        // n1 = 32nt + (r&3) + 8(r>>2) + 4h. Bias (LDS broadcast f32x4) + silu,
        // pack pairs to f16x2, then exchange half the dwords with lane^32
        // (same row l31, other n1 residues).
        unsigned int K0[8], K1[8], R0[8], R1[8];   // indexed by kt2 = 2nt+i
#pragma unroll
        for (int nt = 0; nt < 4; ++nt) {
            unsigned int D[4][2];
#pragma unroll
            for (int rr = 0; rr < 4; ++rr) {
                // b1 values for n1 = 32nt+8rr+4h+{0,1,2,3}; aligned 16B, 2 addrs/wave
                const f32x4 bv = *(const f32x4*)&b1s[32 * nt + 8 * rr + 4 * h];
#pragma unroll
                for (int qp = 0; qp < 2; ++qp) {
                    const int r  = 4 * rr + 2 * qp;
                    const float z0 = acc[nt][r]     + bv[2 * qp];
                    const float z1 = acc[nt][r + 1] + bv[2 * qp + 1];
                    f16x2 p; p.x = (f16)silu_f(z0); p.y = (f16)silu_f(z1);
                    D[rr][qp] = __builtin_bit_cast(unsigned int, p);
                }
            }
#pragma unroll
            for (int i = 0; i < 2; ++i) {
                const unsigned int s0 = h ? D[2 * i][0] : D[2 * i + 1][0];
                const unsigned int s1 = h ? D[2 * i][1] : D[2 * i + 1][1];
                const unsigned int r0 = (unsigned int)__shfl_xor((int)s0, 32, 64);
                const unsigned int r1 = (unsigned int)__shfl_xor((int)s1, 32, 64);
                K0[2 * nt + i] = h ? D[2 * i + 1][0] : D[2 * i][0];
                K1[2 * nt + i] = h ? D[2 * i + 1][1] : D[2 * i][1];
                R0[2 * nt + i] = r0;
                R1[2 * nt + i] = r1;
            }
        }

        // ---- layer 2: assemble arg2 frags in-register (x1[row=l31][k=16kt+8h+j]):
        // kept pair at dword slots 2h..2h+1, received pair at 2(1-h)..; 32 MFMAs.
        f32x16 acc2[4];
#pragma unroll
        for (int nt = 0; nt < 4; ++nt)
#pragma unroll
            for (int r = 0; r < 16; ++r) acc2[nt][r] = 0.0f;
#pragma unroll
        for (int kt = 0; kt < 8; ++kt) {
            U8 bf;
            bf.u[0] = h ? R0[kt] : K0[kt];
            bf.u[1] = h ? R1[kt] : K1[kt];
            bf.u[2] = h ? K0[kt] : R0[kt];
            bf.u[3] = h ? K1[kt] : R1[kt];
#pragma unroll
            for (int nt = 0; nt < 4; ++nt) {
                acc2[nt] = __builtin_amdgcn_mfma_f32_32x32x16_f16(
                    w2f[kt][nt][lane], bf.v, acc2[nt], 0, 0, 0);
            }
        }

        // ---- epilogue 2: bias (LDS broadcast) + silu; lane L = out row (row0+l31);
        // store 16 float4 chunks: cols 32nt+8rr+4h .. +3.
        const size_t rbase = (size_t)(row0 + l31) * DIM;
#pragma unroll
        for (int nt = 0; nt < 4; ++nt) {
#pragma unroll
            for (int rr = 0; rr < 4; ++rr) {
                const f32x4 bv = *(const f32x4*)&b2s[32 * nt + 8 * rr + 4 * h];
                f32x4 o;
#pragma unroll
                for (int q = 0; q < 4; ++q) {
                    const int r = 4 * rr + q;
                    o[q] = silu_f(acc2[nt][r] + bv[q]);
                }
                *(f32x4*)&out[rbase + 32 * nt + 8 * rr + 4 * h] = o;
            }
        }
    }
}

extern "C" void kernel_launch(void* const* d_in, const int* in_sizes, int n_in,
                              void* d_out, int out_size, void* d_ws, size_t ws_size,
                              hipStream_t stream) {
    const float* t  = (const float*)d_in[0];
    const float* W1 = (const float*)d_in[1];
    const float* b1 = (const float*)d_in[2];
    const float* W2 = (const float*)d_in[3];
    const float* b2 = (const float*)d_in[4];
    float* out = (float*)d_out;
    const int B = in_sizes[0];
    const int ntiles = B >> 8;              // 256 rows per block-tile
    // 65.5 KB LDS -> 2 blocks/CU; 512 blocks x 2 tiles each
    int grid = ntiles < 512 ? ntiles : 512;
    ts_mlp_kernel<<<dim3(grid), dim3(512), 0, stream>>>(t, W1, b1, W2, b2, out, B);
}